// Round 6
// baseline (462.113 us; speedup 1.0000x reference)
//
#include <hip/hip_runtime.h>
#include <hip/hip_bf16.h>

typedef __attribute__((ext_vector_type(8))) short bf16x8;
typedef __attribute__((ext_vector_type(8))) unsigned short u16x8;
typedef __attribute__((ext_vector_type(16))) float f32x16;
typedef __attribute__((ext_vector_type(4))) float f32x4;
typedef __attribute__((ext_vector_type(4))) int i32x4;
typedef __attribute__((ext_vector_type(4))) unsigned int u32x4;

__device__ __forceinline__ unsigned short f2bf(float f) {
    union { __hip_bfloat16 h; unsigned short u; } cv;
    cv.h = __float2bfloat16(f);
    return cv.u;
}
__device__ __forceinline__ unsigned int pack2bf(float a, float b) {
    return (unsigned int)f2bf(a) | ((unsigned int)f2bf(b) << 16);
}

__global__ __launch_bounds__(256, 4) void attn_fwd(
    const float* __restrict__ Vg, const float* __restrict__ Kg,
    const float* __restrict__ Qg, const int* __restrict__ Mg,
    float* __restrict__ Og)
{
    constexpr int S = 2048, H = 16, D = 64, SROW = H * D;
    constexpr float CST = 0.03125f * 1.44269504088896f;  // (1/sqrt(1024))·log2(e)

    // 40 KB: K dbuf 16K | VT dbuf 16K | bias 8K. Epilogue reuses first 32K as O^T.
    __shared__ char smem[40960];
    unsigned short* Kl  = (unsigned short*)smem;             // [2][64*64] bf16 [kv][d]
    unsigned short* Vt  = (unsigned short*)(smem + 16384);   // [2][64*64] bf16 [d][kv]
    float*          Bs  = (float*)(smem + 32768);            // [2048] mask bias

    const int tid  = threadIdx.x;
    const int lane = tid & 63;
    const int w    = tid >> 6;
    const int c5   = lane & 31;   // fragment row/col index (= this lane's q-row)
    const int hi   = lane >> 5;   // half-wave index

    // T1: bijective XCD swizzle (1024 blocks, 8 XCDs, 128 per XCD)
    const int logical = (blockIdx.x & 7) * 128 + (blockIdx.x >> 3);
    const int qb  = logical & 15;
    const int h   = (logical >> 4) & 15;
    const int b   = logical >> 8;

    const int q0 = qb * 128 + w * 32;   // 32 q-rows per wave

    const size_t base = ((size_t)b * S * H + h) * D;
    const float* Qp = Qg + base;
    const float* Kp = Kg + base;
    const float* Vp = Vg + base;
    float*       Op = Og + base;

    // ---- mask -> bias table (once per block) ----
    {
        const int* mp = Mg + b * S + tid * 8;
        i32x4 m0 = *(const i32x4*)mp;
        i32x4 m1 = *(const i32x4*)(mp + 4);
        f32x4 b0, b1;
#pragma unroll
        for (int j = 0; j < 4; ++j) {
            b0[j] = m0[j] ? 0.0f : -1e20f;
            b1[j] = m1[j] ? 0.0f : -1e20f;
        }
        *(f32x4*)(Bs + tid * 8)     = b0;
        *(f32x4*)(Bs + tid * 8 + 4) = b1;
    }

    // staging coords (same as prior rounds)
    const int kr  = tid >> 2;          // K-stage row 0..63
    const int kc0 = (tid & 3) << 4;    // K-stage col {0,16,32,48}
    const int vk  = (tid & 31) << 1;   // V-stage kv row pair base
    const int vd0 = (tid >> 5) << 3;   // V-stage d base {0..56}

    // ---- Q fragments: lane holds Q[q=q0+c5][d=16kc+8hi .. +7] (B-operand) ----
    bf16x8 qf[4];
#pragma unroll
    for (int kc = 0; kc < 4; ++kc) {
        const float* qr = Qp + (size_t)(q0 + c5) * SROW + kc * 16 + hi * 8;
        f32x4 x = *(const f32x4*)qr;
        f32x4 y = *(const f32x4*)(qr + 4);
        bf16x8 f;
#pragma unroll
        for (int j = 0; j < 4; ++j) { f[j] = (short)f2bf(x[j]); f[4 + j] = (short)f2bf(y[j]); }
        qf[kc] = f;
    }

    f32x16 oacc[2];
#pragma unroll
    for (int dt = 0; dt < 2; ++dt)
#pragma unroll
        for (int r = 0; r < 16; ++r) oacc[dt][r] = 0.0f;
    float m_run = -INFINITY, l_run = 0.0f;   // per-lane stats for q-row c5

    f32x4 kstg[4], vstg[4];

    auto STAGE_LOAD = [&](int t) {
        const int k0 = t * 64;
        const float* src = Kp + (size_t)(k0 + kr) * SROW + kc0;
        kstg[0] = *(const f32x4*)(src);
        kstg[1] = *(const f32x4*)(src + 4);
        kstg[2] = *(const f32x4*)(src + 8);
        kstg[3] = *(const f32x4*)(src + 12);
        const float* s0 = Vp + (size_t)(k0 + vk) * SROW + vd0;
        const float* s1 = s0 + SROW;
        vstg[0] = *(const f32x4*)(s0);
        vstg[1] = *(const f32x4*)(s0 + 4);
        vstg[2] = *(const f32x4*)(s1);
        vstg[3] = *(const f32x4*)(s1 + 4);
    };

    auto STAGE_WRITE = [&](int buf) {
        u16x8 w0, w1;
#pragma unroll
        for (int j = 0; j < 4; ++j) {
            w0[j]     = f2bf(kstg[0][j]);
            w0[4 + j] = f2bf(kstg[1][j]);
            w1[j]     = f2bf(kstg[2][j]);
            w1[4 + j] = f2bf(kstg[3][j]);
        }
        char* kb = (char*)(Kl + buf * 4096) + kr * 128;
        *(u16x8*)(kb + ((kc0 * 2)      ^ ((kr & 7) << 4))) = w0;
        *(u16x8*)(kb + ((kc0 * 2 + 16) ^ ((kr & 7) << 4))) = w1;
        char* vbase = (char*)(Vt + buf * 4096);
#pragma unroll
        for (int j = 0; j < 8; ++j) {
            int d = vd0 + j;
            float lo = (j < 4) ? vstg[0][j] : vstg[1][j - 4];
            float hv = (j < 4) ? vstg[2][j] : vstg[3][j - 4];
            unsigned int val = (unsigned int)f2bf(lo) | ((unsigned int)f2bf(hv) << 16);
            *(unsigned int*)(vbase + d * 128 + ((vk * 2) ^ ((d & 7) << 4))) = val;
        }
    };

    // ---- prologue ----
    STAGE_LOAD(0);
    STAGE_WRITE(0);
    __syncthreads();   // also publishes the bias table

    for (int t = 0; t < 32; ++t) {
        const int cur = t & 1;
        const int nxt = cur ^ 1;
        const int k0  = t * 64;

        if (t < 31) STAGE_LOAD(t + 1);   // T14: issue early, write after compute

        // bias reads (broadcast, conflict-free): bv[tt][rc] covers kv=k0+32tt+8rc+4hi+0..3
        f32x4 bv[2][4];
#pragma unroll
        for (int tt = 0; tt < 2; ++tt)
#pragma unroll
            for (int rc = 0; rc < 4; ++rc)
                bv[tt][rc] = *(const f32x4*)(Bs + k0 + 32 * tt + 8 * rc + 4 * hi);

        // ---- swapped QK^T (32x32x16): sacc[tt] r -> S^T[kv=32tt+(r&3)+8(r>>2)+4hi][q=c5]
        f32x16 sacc[2];
#pragma unroll
        for (int tt = 0; tt < 2; ++tt)
#pragma unroll
            for (int r = 0; r < 16; ++r) sacc[tt][r] = 0.0f;

        __builtin_amdgcn_s_setprio(1);
#pragma unroll
        for (int tt = 0; tt < 2; ++tt) {
#pragma unroll
            for (int kc = 0; kc < 4; ++kc) {
                bf16x8 kf = *(const bf16x8*)((char*)(Kl + cur * 4096) +
                            (32 * tt + c5) * 128 + ((kc * 32 + hi * 16) ^ ((c5 & 7) << 4)));
                sacc[tt] = __builtin_amdgcn_mfma_f32_32x32x16_bf16(
                    kf, qf[kc], sacc[tt], 0, 0, 0);
            }
        }
        __builtin_amdgcn_s_setprio(0);

        // ---- scale + mask bias (one fma each) ----
#pragma unroll
        for (int tt = 0; tt < 2; ++tt)
#pragma unroll
            for (int r = 0; r < 16; ++r)
                sacc[tt][r] = sacc[tt][r] * CST + bv[tt][r >> 2][r & 3];

        // ---- online softmax: in-register 32-value reduce + 1 xor-32 ----
        float mx = sacc[0][0];
#pragma unroll
        for (int r = 1; r < 16; ++r) mx = fmaxf(mx, sacc[0][r]);
#pragma unroll
        for (int r = 0; r < 16; ++r) mx = fmaxf(mx, sacc[1][r]);
        mx = fmaxf(mx, __shfl_xor(mx, 32));

        float mn = fmaxf(m_run, mx);
        float alpha = __builtin_amdgcn_exp2f(m_run - mn);
        m_run = mn;

#pragma unroll
        for (int tt = 0; tt < 2; ++tt)
#pragma unroll
            for (int r = 0; r < 16; ++r)
                sacc[tt][r] = __builtin_amdgcn_exp2f(sacc[tt][r] - mn);

        float sm = 0.0f;
#pragma unroll
        for (int tt = 0; tt < 2; ++tt)
#pragma unroll
            for (int r = 0; r < 16; ++r) sm += sacc[tt][r];
        sm += __shfl_xor(sm, 32);
        l_run = l_run * alpha + sm;

#pragma unroll
        for (int dt = 0; dt < 2; ++dt)
#pragma unroll
            for (int r = 0; r < 16; ++r) oacc[dt][r] *= alpha;

        // ---- P -> bf16 pack: pk[tt][rc][w] = P[q=c5][kv=32tt+8rc+4hi+{2w,2w+1}] ----
        unsigned int pk[2][4][2];
#pragma unroll
        for (int tt = 0; tt < 2; ++tt)
#pragma unroll
            for (int rc = 0; rc < 4; ++rc) {
                pk[tt][rc][0] = pack2bf(sacc[tt][4 * rc],     sacc[tt][4 * rc + 1]);
                pk[tt][rc][1] = pack2bf(sacc[tt][4 * rc + 2], sacc[tt][4 * rc + 3]);
            }

        // ---- in-register exchange (xor-32) -> pa[ks]: B-frag P^T[k=8hi+j][q=c5] ----
        bf16x8 pa[4];
#pragma unroll
        for (int tt = 0; tt < 2; ++tt) {
#pragma unroll
            for (int pr = 0; pr < 2; ++pr) {
                unsigned int s0 = hi ? pk[tt][2 * pr][0] : pk[tt][2 * pr + 1][0];
                unsigned int s1 = hi ? pk[tt][2 * pr][1] : pk[tt][2 * pr + 1][1];
                unsigned int r0 = (unsigned int)__shfl_xor((int)s0, 32);
                unsigned int r1 = (unsigned int)__shfl_xor((int)s1, 32);
                u32x4 pw;
                pw[0] = hi ? r0 : pk[tt][2 * pr][0];
                pw[1] = hi ? r1 : pk[tt][2 * pr][1];
                pw[2] = hi ? pk[tt][2 * pr + 1][0] : r0;
                pw[3] = hi ? pk[tt][2 * pr + 1][1] : r1;
                pa[2 * tt + pr] = __builtin_bit_cast(bf16x8, pw);
            }
        }

        // ---- PV (32x32x16): O^T[dout][q] += V^T[dout][kv] . P^T[kv][q] ----
        __builtin_amdgcn_s_setprio(1);
#pragma unroll
        for (int dt = 0; dt < 2; ++dt) {
#pragma unroll
            for (int ks = 0; ks < 4; ++ks) {
                bf16x8 vf = *(const bf16x8*)((char*)(Vt + cur * 4096) +
                            (32 * dt + c5) * 128 + ((ks * 32 + hi * 16) ^ ((c5 & 7) << 4)));
                oacc[dt] = __builtin_amdgcn_mfma_f32_32x32x16_bf16(
                    vf, pa[ks], oacc[dt], 0, 0, 0);
            }
        }
        __builtin_amdgcn_s_setprio(0);

        if (t < 31) STAGE_WRITE(nxt);
        __syncthreads();
    }

    // ---- epilogue: O^T/l -> LDS transpose -> coalesced fp32 store ----
    float rinv = 1.0f / l_run;
    float* OT = (float*)smem;   // [128 q][64 d], 256 B rows, XOR-swizzled
    {
        const int row = w * 32 + c5;
#pragma unroll
        for (int dt = 0; dt < 2; ++dt)
#pragma unroll
            for (int rc = 0; rc < 4; ++rc) {
                f32x4 v;
#pragma unroll
                for (int i = 0; i < 4; ++i) v[i] = oacc[dt][4 * rc + i] * rinv;
                *(f32x4*)((char*)OT + row * 256 +
                          (((32 * dt + 8 * rc + 4 * hi) * 4) ^ ((row & 7) << 4))) = v;
            }
    }
    __syncthreads();
    {
        const int row  = tid >> 1;          // 0..127
        const int half = tid & 1;           // d-half
        const int qrow = qb * 128 + row;
#pragma unroll
        for (int k = 0; k < 8; ++k) {
            f32x4 v = *(const f32x4*)((char*)OT + row * 256 +
                       ((128 * half + 16 * k) ^ ((row & 7) << 4)));
            *(f32x4*)(Op + (size_t)qrow * SROW + 32 * half + 4 * k) = v;
        }
    }
}

extern "C" void kernel_launch(void* const* d_in, const int* in_sizes, int n_in,
                              void* d_out, int out_size, void* d_ws, size_t ws_size,
                              hipStream_t stream) {
    const float* V = (const float*)d_in[0];
    const float* K = (const float*)d_in[1];
    const float* Q = (const float*)d_in[2];
    const int*   M = (const int*)d_in[3];
    float*       O = (float*)d_out;
    // grid: 16 q-blocks x 16 heads x 4 batch = 1024 blocks (exactly 4/CU), 256 threads
    attn_fwd<<<dim3(1024), dim3(256), 0, stream>>>(V, K, Q, M, O);
}

// Round 7
// 151.856 us; speedup vs baseline: 3.0431x; 3.0431x over previous
//
#include <hip/hip_runtime.h>
#include <hip/hip_bf16.h>

typedef __attribute__((ext_vector_type(8))) short bf16x8;
typedef __attribute__((ext_vector_type(8))) unsigned short u16x8;
typedef __attribute__((ext_vector_type(16))) float f32x16;
typedef __attribute__((ext_vector_type(4))) float f32x4;
typedef __attribute__((ext_vector_type(4))) int i32x4;
typedef __attribute__((ext_vector_type(4))) unsigned int u32x4;

__device__ __forceinline__ unsigned short f2bf(float f) {
    union { __hip_bfloat16 h; unsigned short u; } cv;
    cv.h = __float2bfloat16(f);
    return cv.u;
}
__device__ __forceinline__ unsigned int pack2bf(float a, float b) {
    return (unsigned int)f2bf(a) | ((unsigned int)f2bf(b) << 16);
}

// (256,2): 256-VGPR cap. The (256,4)/128-cap variant spilled oacc/sacc to
// scratch -> 1.6 GB HBM traffic/dispatch (round 6). High-VGPR deep waves
// beat high occupancy for this structure (m214).
__global__ __launch_bounds__(256, 2) void attn_fwd(
    const float* __restrict__ Vg, const float* __restrict__ Kg,
    const float* __restrict__ Qg, const int* __restrict__ Mg,
    float* __restrict__ Og)
{
    constexpr int S = 2048, H = 16, D = 64, SROW = H * D;
    constexpr float CST = 0.03125f * 1.44269504088896f;  // (1/sqrt(1024))·log2(e)

    // 40 KB: K dbuf 16K | VT dbuf 16K | bias 8K. Epilogue reuses first 32K as O^T.
    __shared__ char smem[40960];
    unsigned short* Kl  = (unsigned short*)smem;             // [2][64*64] bf16 [kv][d]
    unsigned short* Vt  = (unsigned short*)(smem + 16384);   // [2][64*64] bf16 [d][kv]
    float*          Bs  = (float*)(smem + 32768);            // [2048] mask bias

    const int tid  = threadIdx.x;
    const int lane = tid & 63;
    const int w    = tid >> 6;
    const int c5   = lane & 31;   // fragment row/col index (= this lane's q-row)
    const int hi   = lane >> 5;   // half-wave index

    // T1: bijective XCD swizzle (1024 blocks, 8 XCDs, 128 per XCD)
    const int logical = (blockIdx.x & 7) * 128 + (blockIdx.x >> 3);
    const int qb  = logical & 15;
    const int h   = (logical >> 4) & 15;
    const int b   = logical >> 8;

    const int q0 = qb * 128 + w * 32;   // 32 q-rows per wave

    const size_t base = ((size_t)b * S * H + h) * D;
    const float* Qp = Qg + base;
    const float* Kp = Kg + base;
    const float* Vp = Vg + base;
    float*       Op = Og + base;

    // ---- mask -> bias table (once per block) ----
    {
        const int* mp = Mg + b * S + tid * 8;
        i32x4 m0 = *(const i32x4*)mp;
        i32x4 m1 = *(const i32x4*)(mp + 4);
        f32x4 b0, b1;
#pragma unroll
        for (int j = 0; j < 4; ++j) {
            b0[j] = m0[j] ? 0.0f : -1e20f;
            b1[j] = m1[j] ? 0.0f : -1e20f;
        }
        *(f32x4*)(Bs + tid * 8)     = b0;
        *(f32x4*)(Bs + tid * 8 + 4) = b1;
    }

    // staging coords
    const int kr  = tid >> 2;          // K-stage row 0..63
    const int kc0 = (tid & 3) << 4;    // K-stage col {0,16,32,48}
    const int vk  = (tid & 31) << 1;   // V-stage kv row pair base
    const int vd0 = (tid >> 5) << 3;   // V-stage d base {0..56}

    // ---- Q fragments: lane holds Q[q=q0+c5][d=16kc+8hi .. +7] (B-operand) ----
    bf16x8 qf[4];
#pragma unroll
    for (int kc = 0; kc < 4; ++kc) {
        const float* qr = Qp + (size_t)(q0 + c5) * SROW + kc * 16 + hi * 8;
        f32x4 x = *(const f32x4*)qr;
        f32x4 y = *(const f32x4*)(qr + 4);
        bf16x8 f;
#pragma unroll
        for (int j = 0; j < 4; ++j) { f[j] = (short)f2bf(x[j]); f[4 + j] = (short)f2bf(y[j]); }
        qf[kc] = f;
    }

    f32x16 oacc[2];
#pragma unroll
    for (int dt = 0; dt < 2; ++dt)
#pragma unroll
        for (int r = 0; r < 16; ++r) oacc[dt][r] = 0.0f;
    float m_run = -INFINITY, l_run = 0.0f;   // per-lane stats for q-row c5

    f32x4 kstg[4], vstg[4];

    auto STAGE_LOAD = [&](int t) {
        const int k0 = t * 64;
        const float* src = Kp + (size_t)(k0 + kr) * SROW + kc0;
        kstg[0] = *(const f32x4*)(src);
        kstg[1] = *(const f32x4*)(src + 4);
        kstg[2] = *(const f32x4*)(src + 8);
        kstg[3] = *(const f32x4*)(src + 12);
        const float* s0 = Vp + (size_t)(k0 + vk) * SROW + vd0;
        const float* s1 = s0 + SROW;
        vstg[0] = *(const f32x4*)(s0);
        vstg[1] = *(const f32x4*)(s0 + 4);
        vstg[2] = *(const f32x4*)(s1);
        vstg[3] = *(const f32x4*)(s1 + 4);
    };

    auto STAGE_WRITE = [&](int buf) {
        u16x8 w0, w1;
#pragma unroll
        for (int j = 0; j < 4; ++j) {
            w0[j]     = f2bf(kstg[0][j]);
            w0[4 + j] = f2bf(kstg[1][j]);
            w1[j]     = f2bf(kstg[2][j]);
            w1[4 + j] = f2bf(kstg[3][j]);
        }
        char* kb = (char*)(Kl + buf * 4096) + kr * 128;
        *(u16x8*)(kb + ((kc0 * 2)      ^ ((kr & 7) << 4))) = w0;
        *(u16x8*)(kb + ((kc0 * 2 + 16) ^ ((kr & 7) << 4))) = w1;
        char* vbase = (char*)(Vt + buf * 4096);
#pragma unroll
        for (int j = 0; j < 8; ++j) {
            int d = vd0 + j;
            float lo = (j < 4) ? vstg[0][j] : vstg[1][j - 4];
            float hv = (j < 4) ? vstg[2][j] : vstg[3][j - 4];
            unsigned int val = (unsigned int)f2bf(lo) | ((unsigned int)f2bf(hv) << 16);
            *(unsigned int*)(vbase + d * 128 + ((vk * 2) ^ ((d & 7) << 4))) = val;
        }
    };

    // ---- prologue ----
    STAGE_LOAD(0);
    STAGE_WRITE(0);
    __syncthreads();   // also publishes the bias table

    for (int t = 0; t < 32; ++t) {
        const int cur = t & 1;
        const int nxt = cur ^ 1;
        const int k0  = t * 64;

        if (t < 31) STAGE_LOAD(t + 1);   // T14: issue early, write after compute

        // bias reads (broadcast, conflict-free): bv[tt][rc] covers kv=k0+32tt+8rc+4hi+0..3
        f32x4 bv[2][4];
#pragma unroll
        for (int tt = 0; tt < 2; ++tt)
#pragma unroll
            for (int rc = 0; rc < 4; ++rc)
                bv[tt][rc] = *(const f32x4*)(Bs + k0 + 32 * tt + 8 * rc + 4 * hi);

        // ---- swapped QK^T (32x32x16): sacc[tt] r -> S^T[kv=32tt+(r&3)+8(r>>2)+4hi][q=c5]
        f32x16 sacc[2];
#pragma unroll
        for (int tt = 0; tt < 2; ++tt)
#pragma unroll
            for (int r = 0; r < 16; ++r) sacc[tt][r] = 0.0f;

        __builtin_amdgcn_s_setprio(1);
#pragma unroll
        for (int tt = 0; tt < 2; ++tt) {
#pragma unroll
            for (int kc = 0; kc < 4; ++kc) {
                bf16x8 kf = *(const bf16x8*)((char*)(Kl + cur * 4096) +
                            (32 * tt + c5) * 128 + ((kc * 32 + hi * 16) ^ ((c5 & 7) << 4)));
                sacc[tt] = __builtin_amdgcn_mfma_f32_32x32x16_bf16(
                    kf, qf[kc], sacc[tt], 0, 0, 0);
            }
        }
        __builtin_amdgcn_s_setprio(0);

        // ---- scale + mask bias (one fma each) ----
#pragma unroll
        for (int tt = 0; tt < 2; ++tt)
#pragma unroll
            for (int r = 0; r < 16; ++r)
                sacc[tt][r] = sacc[tt][r] * CST + bv[tt][r >> 2][r & 3];

        // ---- online softmax: in-register 32-value reduce + 1 xor-32 ----
        float mx = sacc[0][0];
#pragma unroll
        for (int r = 1; r < 16; ++r) mx = fmaxf(mx, sacc[0][r]);
#pragma unroll
        for (int r = 0; r < 16; ++r) mx = fmaxf(mx, sacc[1][r]);
        mx = fmaxf(mx, __shfl_xor(mx, 32));

        float mn = fmaxf(m_run, mx);
        float alpha = __builtin_amdgcn_exp2f(m_run - mn);
        m_run = mn;

#pragma unroll
        for (int tt = 0; tt < 2; ++tt)
#pragma unroll
            for (int r = 0; r < 16; ++r)
                sacc[tt][r] = __builtin_amdgcn_exp2f(sacc[tt][r] - mn);

        float sm = 0.0f;
#pragma unroll
        for (int tt = 0; tt < 2; ++tt)
#pragma unroll
            for (int r = 0; r < 16; ++r) sm += sacc[tt][r];
        sm += __shfl_xor(sm, 32);
        l_run = l_run * alpha + sm;

#pragma unroll
        for (int dt = 0; dt < 2; ++dt)
#pragma unroll
            for (int r = 0; r < 16; ++r) oacc[dt][r] *= alpha;

        // ---- P -> bf16 pack: pk[tt][rc][w] = P[q=c5][kv=32tt+8rc+4hi+{2w,2w+1}] ----
        unsigned int pk[2][4][2];
#pragma unroll
        for (int tt = 0; tt < 2; ++tt)
#pragma unroll
            for (int rc = 0; rc < 4; ++rc) {
                pk[tt][rc][0] = pack2bf(sacc[tt][4 * rc],     sacc[tt][4 * rc + 1]);
                pk[tt][rc][1] = pack2bf(sacc[tt][4 * rc + 2], sacc[tt][4 * rc + 3]);
            }

        // ---- in-register exchange (xor-32) -> pa[ks]: B-frag P^T[k=8hi+j][q=c5] ----
        bf16x8 pa[4];
#pragma unroll
        for (int tt = 0; tt < 2; ++tt) {
#pragma unroll
            for (int pr = 0; pr < 2; ++pr) {
                unsigned int s0 = hi ? pk[tt][2 * pr][0] : pk[tt][2 * pr + 1][0];
                unsigned int s1 = hi ? pk[tt][2 * pr][1] : pk[tt][2 * pr + 1][1];
                unsigned int r0 = (unsigned int)__shfl_xor((int)s0, 32);
                unsigned int r1 = (unsigned int)__shfl_xor((int)s1, 32);
                u32x4 pw;
                pw[0] = hi ? r0 : pk[tt][2 * pr][0];
                pw[1] = hi ? r1 : pk[tt][2 * pr][1];
                pw[2] = hi ? pk[tt][2 * pr + 1][0] : r0;
                pw[3] = hi ? pk[tt][2 * pr + 1][1] : r1;
                pa[2 * tt + pr] = __builtin_bit_cast(bf16x8, pw);
            }
        }

        // ---- PV (32x32x16): O^T[dout][q] += V^T[dout][kv] . P^T[kv][q] ----
        __builtin_amdgcn_s_setprio(1);
#pragma unroll
        for (int dt = 0; dt < 2; ++dt) {
#pragma unroll
            for (int ks = 0; ks < 4; ++ks) {
                bf16x8 vf = *(const bf16x8*)((char*)(Vt + cur * 4096) +
                            (32 * dt + c5) * 128 + ((ks * 32 + hi * 16) ^ ((c5 & 7) << 4)));
                oacc[dt] = __builtin_amdgcn_mfma_f32_32x32x16_bf16(
                    vf, pa[ks], oacc[dt], 0, 0, 0);
            }
        }
        __builtin_amdgcn_s_setprio(0);

        if (t < 31) STAGE_WRITE(nxt);
        __syncthreads();
    }

    // ---- epilogue: O^T/l -> LDS transpose -> coalesced fp32 store ----
    float rinv = 1.0f / l_run;
    float* OT = (float*)smem;   // [128 q][64 d], 256 B rows, XOR-swizzled
    {
        const int row = w * 32 + c5;
#pragma unroll
        for (int dt = 0; dt < 2; ++dt)
#pragma unroll
            for (int rc = 0; rc < 4; ++rc) {
                f32x4 v;
#pragma unroll
                for (int i = 0; i < 4; ++i) v[i] = oacc[dt][4 * rc + i] * rinv;
                *(f32x4*)((char*)OT + row * 256 +
                          (((32 * dt + 8 * rc + 4 * hi) * 4) ^ ((row & 7) << 4))) = v;
            }
    }
    __syncthreads();
    {
        const int row  = tid >> 1;          // 0..127
        const int half = tid & 1;           // d-half
        const int qrow = qb * 128 + row;
#pragma unroll
        for (int k = 0; k < 8; ++k) {
            f32x4 v = *(const f32x4*)((char*)OT + row * 256 +
                       ((128 * half + 16 * k) ^ ((row & 7) << 4)));
            *(f32x4*)(Op + (size_t)qrow * SROW + 32 * half + 4 * k) = v;
        }
    }
}

extern "C" void kernel_launch(void* const* d_in, const int* in_sizes, int n_in,
                              void* d_out, int out_size, void* d_ws, size_t ws_size,
                              hipStream_t stream) {
    const float* V = (const float*)d_in[0];
    const float* K = (const float*)d_in[1];
    const float* Q = (const float*)d_in[2];
    const int*   M = (const int*)d_in[3];
    float*       O = (float*)d_out;
    // grid: 16 q-blocks x 16 heads x 4 batch = 1024 blocks, 256 threads
    attn_fwd<<<dim3(1024), dim3(256), 0, stream>>>(V, K, Q, M, O);
}

// Round 8
// 142.638 us; speedup vs baseline: 3.2398x; 1.0646x over previous
//
#include <hip/hip_runtime.h>
#include <hip/hip_bf16.h>

typedef __attribute__((ext_vector_type(8))) short bf16x8;
typedef __attribute__((ext_vector_type(8))) unsigned short u16x8;
typedef __attribute__((ext_vector_type(16))) float f32x16;
typedef __attribute__((ext_vector_type(4))) float f32x4;
typedef __attribute__((ext_vector_type(4))) int i32x4;
typedef __attribute__((ext_vector_type(4))) unsigned int u32x4;

__device__ __forceinline__ unsigned short f2bf(float f) {
    union { __hip_bfloat16 h; unsigned short u; } cv;
    cv.h = __float2bfloat16(f);
    return cv.u;
}
__device__ __forceinline__ unsigned int pack2bf(float a, float b) {
    return (unsigned int)f2bf(a) | ((unsigned int)f2bf(b) << 16);
}
#define MAX4(v, i) fmaxf(fmaxf(v[i], v[(i)+1]), fmaxf(v[(i)+2], v[(i)+3]))
#define SUM4(v, i) ((v[i] + v[(i)+1]) + (v[(i)+2] + v[(i)+3]))

// (256,2): 256-VGPR cap — the 128-cap variant spilled accumulators (round 6:
// 1.6 GB scratch traffic). High-VGPR deep waves beat occupancy here (m214).
__global__ __launch_bounds__(256, 2) void attn_fwd(
    const float* __restrict__ Vg, const float* __restrict__ Kg,
    const float* __restrict__ Qg, const int* __restrict__ Mg,
    float* __restrict__ Og)
{
    constexpr int S = 2048, H = 16, D = 64, SROW = H * D;
    constexpr float CST = 0.03125f * 1.44269504088896f;  // (1/sqrt(1024))·log2(e)

    // 32 KB: K dbuf 16K | VT dbuf 16K. Epilogue reuses it as O^T.
    __shared__ char smem[32768];
    __shared__ int Tf[32];                                   // per-KV-tile mask flags
    unsigned short* Kl  = (unsigned short*)smem;             // [2][64*64] bf16 [kv][d]
    unsigned short* Vt  = (unsigned short*)(smem + 16384);   // [2][64*64] bf16 [d][kv]

    const int tid  = threadIdx.x;
    const int lane = tid & 63;
    const int w    = tid >> 6;
    const int c5   = lane & 31;   // fragment row/col index (= this lane's q-row)
    const int hi   = lane >> 5;   // half-wave index

    // T1: bijective XCD swizzle (1024 blocks, 8 XCDs, 128 per XCD)
    const int logical = (blockIdx.x & 7) * 128 + (blockIdx.x >> 3);
    const int qb  = logical & 15;
    const int h   = (logical >> 4) & 15;
    const int b   = logical >> 8;

    const int q0 = qb * 128 + w * 32;   // 32 q-rows per wave

    const size_t base = ((size_t)b * S * H + h) * D;
    const float* Qp = Qg + base;
    const float* Kp = Kg + base;
    const float* Vp = Vg + base;
    float*       Op = Og + base;
    const int*   Mp = Mg + b * S;

    // ---- per-tile mask flags (once per block) ----
    if (tid < 32) Tf[tid] = 0;
    __syncthreads();
    {
        const int* mp = Mp + tid * 8;
        i32x4 m0 = *(const i32x4*)mp;
        i32x4 m1 = *(const i32x4*)(mp + 4);
        int anyz = 0;
#pragma unroll
        for (int j = 0; j < 4; ++j) anyz |= (m0[j] == 0) | (m1[j] == 0);
        if (anyz) atomicOr(&Tf[tid >> 3], 1);
    }

    // staging coords
    const int kr  = tid >> 2;          // K-stage row 0..63
    const int kc0 = (tid & 3) << 4;    // K-stage col {0,16,32,48}
    const int vk  = (tid & 31) << 1;   // V-stage kv row pair base
    const int vd0 = (tid >> 5) << 3;   // V-stage d base {0..56}

    // ---- Q fragments (pre-scaled by CST): lane holds Q[q0+c5][16kc+8hi..+7] ----
    bf16x8 qf[4];
#pragma unroll
    for (int kc = 0; kc < 4; ++kc) {
        const float* qr = Qp + (size_t)(q0 + c5) * SROW + kc * 16 + hi * 8;
        f32x4 x = *(const f32x4*)qr;
        f32x4 y = *(const f32x4*)(qr + 4);
        bf16x8 f;
#pragma unroll
        for (int j = 0; j < 4; ++j) {
            f[j]     = (short)f2bf(x[j] * CST);
            f[4 + j] = (short)f2bf(y[j] * CST);
        }
        qf[kc] = f;
    }

    f32x16 oacc[2];
#pragma unroll
    for (int dt = 0; dt < 2; ++dt)
#pragma unroll
        for (int r = 0; r < 16; ++r) oacc[dt][r] = 0.0f;
    float m_run = -INFINITY, l_run = 0.0f;   // per-lane stats for q-row c5

    f32x4 kstg[4], vstg[4];

    auto STAGE_LOAD = [&](int t) {
        const int k0 = t * 64;
        const float* src = Kp + (size_t)(k0 + kr) * SROW + kc0;
        kstg[0] = *(const f32x4*)(src);
        kstg[1] = *(const f32x4*)(src + 4);
        kstg[2] = *(const f32x4*)(src + 8);
        kstg[3] = *(const f32x4*)(src + 12);
        const float* s0 = Vp + (size_t)(k0 + vk) * SROW + vd0;
        const float* s1 = s0 + SROW;
        vstg[0] = *(const f32x4*)(s0);
        vstg[1] = *(const f32x4*)(s0 + 4);
        vstg[2] = *(const f32x4*)(s1);
        vstg[3] = *(const f32x4*)(s1 + 4);
    };

    auto STAGE_WRITE = [&](int buf) {
        u16x8 w0, w1;
#pragma unroll
        for (int j = 0; j < 4; ++j) {
            w0[j]     = f2bf(kstg[0][j]);
            w0[4 + j] = f2bf(kstg[1][j]);
            w1[j]     = f2bf(kstg[2][j]);
            w1[4 + j] = f2bf(kstg[3][j]);
        }
        char* kb = (char*)(Kl + buf * 4096) + kr * 128;
        *(u16x8*)(kb + ((kc0 * 2)      ^ ((kr & 7) << 4))) = w0;
        *(u16x8*)(kb + ((kc0 * 2 + 16) ^ ((kr & 7) << 4))) = w1;
        char* vbase = (char*)(Vt + buf * 4096);
#pragma unroll
        for (int j = 0; j < 8; ++j) {
            int d = vd0 + j;
            float lo = (j < 4) ? vstg[0][j] : vstg[1][j - 4];
            float hv = (j < 4) ? vstg[2][j] : vstg[3][j - 4];
            unsigned int val = (unsigned int)f2bf(lo) | ((unsigned int)f2bf(hv) << 16);
            *(unsigned int*)(vbase + d * 128 + ((vk * 2) ^ ((d & 7) << 4))) = val;
        }
    };

    // ---- prologue ----
    STAGE_LOAD(0);
    STAGE_WRITE(0);
    __syncthreads();   // also publishes Tf

    for (int t = 0; t < 32; ++t) {
        const int cur = t & 1;
        const int nxt = cur ^ 1;
        const int k0  = t * 64;

        if (t < 31) STAGE_LOAD(t + 1);   // T14: issue early, write after compute

        // ---- swapped QK^T (32x32x16): sacc[tt] r -> S^T[kv=32tt+(r&3)+8(r>>2)+4hi][q=c5]
        // (Q pre-scaled: sacc is directly in log2 space)
        f32x16 sacc[2];
#pragma unroll
        for (int tt = 0; tt < 2; ++tt)
#pragma unroll
            for (int r = 0; r < 16; ++r) sacc[tt][r] = 0.0f;

        __builtin_amdgcn_s_setprio(1);
#pragma unroll
        for (int tt = 0; tt < 2; ++tt) {
#pragma unroll
            for (int kc = 0; kc < 4; ++kc) {
                bf16x8 kf = *(const bf16x8*)((char*)(Kl + cur * 4096) +
                            (32 * tt + c5) * 128 + ((kc * 32 + hi * 16) ^ ((c5 & 7) << 4)));
                sacc[tt] = __builtin_amdgcn_mfma_f32_32x32x16_bf16(
                    kf, qf[kc], sacc[tt], 0, 0, 0);
            }
        }
        __builtin_amdgcn_s_setprio(0);

        // ---- mask (rare slow path; block-uniform branch) ----
        if (Tf[t]) {
            const int* mp = Mp + k0;
#pragma unroll
            for (int tt = 0; tt < 2; ++tt)
#pragma unroll
                for (int rc = 0; rc < 4; ++rc) {
                    i32x4 mv = *(const i32x4*)(mp + 32 * tt + 8 * rc + 4 * hi);
#pragma unroll
                    for (int r = 0; r < 4; ++r)
                        if (!mv[r]) sacc[tt][4 * rc + r] = -1e20f;
                }
        }

        // ---- online softmax: tree max (max3-fusable) + 1 xor-32 ----
        float mA = fmaxf(MAX4(sacc[0], 0), MAX4(sacc[0], 4));
        float mB = fmaxf(MAX4(sacc[0], 8), MAX4(sacc[0], 12));
        float mC = fmaxf(MAX4(sacc[1], 0), MAX4(sacc[1], 4));
        float mD = fmaxf(MAX4(sacc[1], 8), MAX4(sacc[1], 12));
        float mx = fmaxf(fmaxf(mA, mB), fmaxf(mC, mD));
        mx = fmaxf(mx, __shfl_xor(mx, 32));

        // T13 defer-max: skip rescale while max growth <= 8 (P bounded by 2^8)
        if (!__all(mx <= m_run + 8.0f)) {
            float mn = fmaxf(m_run, mx);
            float alpha = __builtin_amdgcn_exp2f(m_run - mn);
            m_run = mn;
            l_run *= alpha;
#pragma unroll
            for (int dt = 0; dt < 2; ++dt)
#pragma unroll
                for (int r = 0; r < 16; ++r) oacc[dt][r] *= alpha;
        }

        // p = exp2(lg - m)
#pragma unroll
        for (int tt = 0; tt < 2; ++tt)
#pragma unroll
            for (int r = 0; r < 16; ++r)
                sacc[tt][r] = __builtin_amdgcn_exp2f(sacc[tt][r] - m_run);

        // row sum: pairwise tree + 1 xor-32
        float sm = (SUM4(sacc[0], 0) + SUM4(sacc[0], 4)) +
                   (SUM4(sacc[0], 8) + SUM4(sacc[0], 12)) +
                   ((SUM4(sacc[1], 0) + SUM4(sacc[1], 4)) +
                    (SUM4(sacc[1], 8) + SUM4(sacc[1], 12)));
        sm += __shfl_xor(sm, 32);
        l_run += sm;

        // ---- P -> bf16 pack: pk[tt][rc][w] = P[q=c5][kv=32tt+8rc+4hi+{2w,2w+1}] ----
        unsigned int pk[2][4][2];
#pragma unroll
        for (int tt = 0; tt < 2; ++tt)
#pragma unroll
            for (int rc = 0; rc < 4; ++rc) {
                pk[tt][rc][0] = pack2bf(sacc[tt][4 * rc],     sacc[tt][4 * rc + 1]);
                pk[tt][rc][1] = pack2bf(sacc[tt][4 * rc + 2], sacc[tt][4 * rc + 3]);
            }

        // ---- in-register exchange (xor-32) -> pa[ks]: B-frag P^T[k=8hi+j][q=c5] ----
        bf16x8 pa[4];
#pragma unroll
        for (int tt = 0; tt < 2; ++tt) {
#pragma unroll
            for (int pr = 0; pr < 2; ++pr) {
                unsigned int s0 = hi ? pk[tt][2 * pr][0] : pk[tt][2 * pr + 1][0];
                unsigned int s1 = hi ? pk[tt][2 * pr][1] : pk[tt][2 * pr + 1][1];
                unsigned int r0 = (unsigned int)__shfl_xor((int)s0, 32);
                unsigned int r1 = (unsigned int)__shfl_xor((int)s1, 32);
                u32x4 pw;
                pw[0] = hi ? r0 : pk[tt][2 * pr][0];
                pw[1] = hi ? r1 : pk[tt][2 * pr][1];
                pw[2] = hi ? pk[tt][2 * pr + 1][0] : r0;
                pw[3] = hi ? pk[tt][2 * pr + 1][1] : r1;
                pa[2 * tt + pr] = __builtin_bit_cast(bf16x8, pw);
            }
        }

        // ---- PV (32x32x16): O^T[dout][q] += V^T[dout][kv] . P^T[kv][q] ----
        __builtin_amdgcn_s_setprio(1);
#pragma unroll
        for (int dt = 0; dt < 2; ++dt) {
#pragma unroll
            for (int ks = 0; ks < 4; ++ks) {
                bf16x8 vf = *(const bf16x8*)((char*)(Vt + cur * 4096) +
                            (32 * dt + c5) * 128 + ((ks * 32 + hi * 16) ^ ((c5 & 7) << 4)));
                oacc[dt] = __builtin_amdgcn_mfma_f32_32x32x16_bf16(
                    vf, pa[ks], oacc[dt], 0, 0, 0);
            }
        }
        __builtin_amdgcn_s_setprio(0);

        if (t < 31) STAGE_WRITE(nxt);
        __syncthreads();
    }

    // ---- epilogue: O^T/l -> LDS transpose -> coalesced fp32 store ----
    float rinv = 1.0f / l_run;
    float* OT = (float*)smem;   // [128 q][64 d], 256 B rows, XOR-swizzled
    {
        const int row = w * 32 + c5;
#pragma unroll
        for (int dt = 0; dt < 2; ++dt)
#pragma unroll
            for (int rc = 0; rc < 4; ++rc) {
                f32x4 v;
#pragma unroll
                for (int i = 0; i < 4; ++i) v[i] = oacc[dt][4 * rc + i] * rinv;
                *(f32x4*)((char*)OT + row * 256 +
                          (((32 * dt + 8 * rc + 4 * hi) * 4) ^ ((row & 7) << 4))) = v;
            }
    }
    __syncthreads();
    {
        const int row  = tid >> 1;          // 0..127
        const int half = tid & 1;           // d-half
        const int qrow = qb * 128 + row;
#pragma unroll
        for (int k = 0; k < 8; ++k) {
            f32x4 v = *(const f32x4*)((char*)OT + row * 256 +
                       ((128 * half + 16 * k) ^ ((row & 7) << 4)));
            *(f32x4*)(Op + (size_t)qrow * SROW + 32 * half + 4 * k) = v;
        }
    }
}

extern "C" void kernel_launch(void* const* d_in, const int* in_sizes, int n_in,
                              void* d_out, int out_size, void* d_ws, size_t ws_size,
                              hipStream_t stream) {
    const float* V = (const float*)d_in[0];
    const float* K = (const float*)d_in[1];
    const float* Q = (const float*)d_in[2];
    const int*   M = (const int*)d_in[3];
    float*       O = (float*)d_out;
    // grid: 16 q-blocks x 16 heads x 4 batch = 1024 blocks, 256 threads
    attn_fwd<<<dim3(1024), dim3(256), 0, stream>>>(V, K, Q, M, O);
}

// Round 9
// 132.335 us; speedup vs baseline: 3.4920x; 1.0779x over previous
//
#include <hip/hip_runtime.h>
#include <hip/hip_bf16.h>

typedef __attribute__((ext_vector_type(8))) short bf16x8;
typedef __attribute__((ext_vector_type(8))) unsigned short u16x8;
typedef __attribute__((ext_vector_type(16))) float f32x16;
typedef __attribute__((ext_vector_type(4))) float f32x4;
typedef __attribute__((ext_vector_type(4))) int i32x4;
typedef __attribute__((ext_vector_type(4))) unsigned int u32x4;

__device__ __forceinline__ unsigned short f2bf(float f) {
    union { __hip_bfloat16 h; unsigned short u; } cv;
    cv.h = __float2bfloat16(f);
    return cv.u;
}
__device__ __forceinline__ unsigned int pack2bf(float a, float b) {
    return (unsigned int)f2bf(a) | ((unsigned int)f2bf(b) << 16);
}
#define MAX4(v, i) fmaxf(fmaxf(v[i], v[(i)+1]), fmaxf(v[(i)+2], v[(i)+3]))
#define SUM4(v, i) ((v[i] + v[(i)+1]) + (v[(i)+2] + v[(i)+3]))

// (256,2): 256-VGPR cap — the 128-cap variant spilled accumulators (round 6:
// 1.6 GB scratch traffic). High-VGPR deep waves beat occupancy here (m214).
// QBLK=256: two q-halves per block -> staging cost amortized 2x (round 9).
__global__ __launch_bounds__(256, 2) void attn_fwd(
    const float* __restrict__ Vg, const float* __restrict__ Kg,
    const float* __restrict__ Qg, const int* __restrict__ Mg,
    float* __restrict__ Og)
{
    constexpr int S = 2048, H = 16, D = 64, SROW = H * D;
    constexpr float CST = 0.03125f * 1.44269504088896f;  // (1/sqrt(1024))·log2(e)

    // 32 KB: K dbuf 16K | VT dbuf 16K. Epilogue reuses it as O^T (2 passes).
    __shared__ char smem[32768];
    __shared__ int Tf[32];                                   // per-KV-tile mask flags
    unsigned short* Kl  = (unsigned short*)smem;             // [2][64*64] bf16 [kv][d]
    unsigned short* Vt  = (unsigned short*)(smem + 16384);   // [2][64*64] bf16 [d][kv]

    const int tid  = threadIdx.x;
    const int lane = tid & 63;
    const int w    = tid >> 6;
    const int c5   = lane & 31;   // fragment row/col index (= this lane's q-row)
    const int hi   = lane >> 5;   // half-wave index

    // T1: bijective XCD swizzle (512 blocks, 8 XCDs, 64 per XCD)
    const int logical = (blockIdx.x & 7) * 64 + (blockIdx.x >> 3);
    const int qb  = logical & 7;          // 8 q-blocks of 256 rows
    const int h   = (logical >> 3) & 15;
    const int b   = logical >> 7;

    const int q0 = qb * 256 + w * 32;     // + 128*h2 + c5 per half

    const size_t base = ((size_t)b * S * H + h) * D;
    const float* Qp = Qg + base;
    const float* Kp = Kg + base;
    const float* Vp = Vg + base;
    float*       Op = Og + base;
    const int*   Mp = Mg + b * S;

    // ---- per-tile mask flags (once per block) ----
    if (tid < 32) Tf[tid] = 0;
    __syncthreads();
    {
        const int* mp = Mp + tid * 8;
        i32x4 m0 = *(const i32x4*)mp;
        i32x4 m1 = *(const i32x4*)(mp + 4);
        int anyz = 0;
#pragma unroll
        for (int j = 0; j < 4; ++j) anyz |= (m0[j] == 0) | (m1[j] == 0);
        if (anyz) atomicOr(&Tf[tid >> 3], 1);
    }

    // staging coords
    const int kr  = tid >> 2;          // K-stage row 0..63
    const int kc0 = (tid & 3) << 4;    // K-stage col {0,16,32,48}
    const int vk  = (tid & 31) << 1;   // V-stage kv row pair base
    const int vd0 = (tid >> 5) << 3;   // V-stage d base {0..56}

    // ---- Q fragments, both halves, pre-scaled by CST ----
    bf16x8 qf[2][4];
#pragma unroll
    for (int h2 = 0; h2 < 2; ++h2)
#pragma unroll
        for (int kc = 0; kc < 4; ++kc) {
            const float* qr = Qp + (size_t)(q0 + 128 * h2 + c5) * SROW + kc * 16 + hi * 8;
            f32x4 x = *(const f32x4*)qr;
            f32x4 y = *(const f32x4*)(qr + 4);
            bf16x8 f;
#pragma unroll
            for (int j = 0; j < 4; ++j) {
                f[j]     = (short)f2bf(x[j] * CST);
                f[4 + j] = (short)f2bf(y[j] * CST);
            }
            qf[h2][kc] = f;
        }

    f32x16 oacc[2][2];
#pragma unroll
    for (int h2 = 0; h2 < 2; ++h2)
#pragma unroll
        for (int dt = 0; dt < 2; ++dt)
#pragma unroll
            for (int r = 0; r < 16; ++r) oacc[h2][dt][r] = 0.0f;
    float m_run[2] = {-INFINITY, -INFINITY};
    float l_run[2] = {0.0f, 0.0f};

    f32x4 kstg[4], vstg[4];

    auto STAGE_LOAD = [&](int t) {
        const int k0 = t * 64;
        const float* src = Kp + (size_t)(k0 + kr) * SROW + kc0;
        kstg[0] = *(const f32x4*)(src);
        kstg[1] = *(const f32x4*)(src + 4);
        kstg[2] = *(const f32x4*)(src + 8);
        kstg[3] = *(const f32x4*)(src + 12);
        const float* s0 = Vp + (size_t)(k0 + vk) * SROW + vd0;
        const float* s1 = s0 + SROW;
        vstg[0] = *(const f32x4*)(s0);
        vstg[1] = *(const f32x4*)(s0 + 4);
        vstg[2] = *(const f32x4*)(s1);
        vstg[3] = *(const f32x4*)(s1 + 4);
    };

    auto STAGE_WRITE = [&](int buf) {
        u16x8 w0, w1;
#pragma unroll
        for (int j = 0; j < 4; ++j) {
            w0[j]     = f2bf(kstg[0][j]);
            w0[4 + j] = f2bf(kstg[1][j]);
            w1[j]     = f2bf(kstg[2][j]);
            w1[4 + j] = f2bf(kstg[3][j]);
        }
        char* kb = (char*)(Kl + buf * 4096) + kr * 128;
        *(u16x8*)(kb + ((kc0 * 2)      ^ ((kr & 7) << 4))) = w0;
        *(u16x8*)(kb + ((kc0 * 2 + 16) ^ ((kr & 7) << 4))) = w1;
        char* vbase = (char*)(Vt + buf * 4096);
#pragma unroll
        for (int j = 0; j < 8; ++j) {
            int d = vd0 + j;
            float lo = (j < 4) ? vstg[0][j] : vstg[1][j - 4];
            float hv = (j < 4) ? vstg[2][j] : vstg[3][j - 4];
            unsigned int val = (unsigned int)f2bf(lo) | ((unsigned int)f2bf(hv) << 16);
            *(unsigned int*)(vbase + d * 128 + ((vk * 2) ^ ((d & 7) << 4))) = val;
        }
    };

    // ---- prologue ----
    STAGE_LOAD(0);
    STAGE_WRITE(0);
    __syncthreads();   // also publishes Tf

    for (int t = 0; t < 32; ++t) {
        const int cur = t & 1;
        const int nxt = cur ^ 1;
        const int k0  = t * 64;

        if (t < 31) STAGE_LOAD(t + 1);   // T14: issue early, write after compute

#pragma unroll
        for (int h2 = 0; h2 < 2; ++h2) {
            // ---- swapped QK^T (32x32x16): S^T[kv=32tt+(r&3)+8(r>>2)+4hi][q=c5] ----
            f32x16 sacc[2];
#pragma unroll
            for (int tt = 0; tt < 2; ++tt)
#pragma unroll
                for (int r = 0; r < 16; ++r) sacc[tt][r] = 0.0f;

            __builtin_amdgcn_s_setprio(1);
#pragma unroll
            for (int tt = 0; tt < 2; ++tt) {
#pragma unroll
                for (int kc = 0; kc < 4; ++kc) {
                    bf16x8 kf = *(const bf16x8*)((char*)(Kl + cur * 4096) +
                                (32 * tt + c5) * 128 + ((kc * 32 + hi * 16) ^ ((c5 & 7) << 4)));
                    sacc[tt] = __builtin_amdgcn_mfma_f32_32x32x16_bf16(
                        kf, qf[h2][kc], sacc[tt], 0, 0, 0);
                }
            }
            __builtin_amdgcn_s_setprio(0);

            // ---- mask (rare slow path; block-uniform branch) ----
            if (Tf[t]) {
                const int* mp = Mp + k0;
#pragma unroll
                for (int tt = 0; tt < 2; ++tt)
#pragma unroll
                    for (int rc = 0; rc < 4; ++rc) {
                        i32x4 mv = *(const i32x4*)(mp + 32 * tt + 8 * rc + 4 * hi);
#pragma unroll
                        for (int r = 0; r < 4; ++r)
                            if (!mv[r]) sacc[tt][4 * rc + r] = -1e20f;
                    }
            }

            // ---- online softmax: tree max + 1 xor-32 ----
            float mA = fmaxf(MAX4(sacc[0], 0), MAX4(sacc[0], 4));
            float mB = fmaxf(MAX4(sacc[0], 8), MAX4(sacc[0], 12));
            float mC = fmaxf(MAX4(sacc[1], 0), MAX4(sacc[1], 4));
            float mD = fmaxf(MAX4(sacc[1], 8), MAX4(sacc[1], 12));
            float mx = fmaxf(fmaxf(mA, mB), fmaxf(mC, mD));
            mx = fmaxf(mx, __shfl_xor(mx, 32));

            // T13 defer-max: skip rescale while max growth <= 8
            if (!__all(mx <= m_run[h2] + 8.0f)) {
                float mn = fmaxf(m_run[h2], mx);
                float alpha = __builtin_amdgcn_exp2f(m_run[h2] - mn);
                m_run[h2] = mn;
                l_run[h2] *= alpha;
#pragma unroll
                for (int dt = 0; dt < 2; ++dt)
#pragma unroll
                    for (int r = 0; r < 16; ++r) oacc[h2][dt][r] *= alpha;
            }

            // p = exp2(lg - m)
#pragma unroll
            for (int tt = 0; tt < 2; ++tt)
#pragma unroll
                for (int r = 0; r < 16; ++r)
                    sacc[tt][r] = __builtin_amdgcn_exp2f(sacc[tt][r] - m_run[h2]);

            // row sum: pairwise tree + 1 xor-32
            float sm = (SUM4(sacc[0], 0) + SUM4(sacc[0], 4)) +
                       (SUM4(sacc[0], 8) + SUM4(sacc[0], 12)) +
                       ((SUM4(sacc[1], 0) + SUM4(sacc[1], 4)) +
                        (SUM4(sacc[1], 8) + SUM4(sacc[1], 12)));
            sm += __shfl_xor(sm, 32);
            l_run[h2] += sm;

            // ---- P -> bf16 pack ----
            unsigned int pk[2][4][2];
#pragma unroll
            for (int tt = 0; tt < 2; ++tt)
#pragma unroll
                for (int rc = 0; rc < 4; ++rc) {
                    pk[tt][rc][0] = pack2bf(sacc[tt][4 * rc],     sacc[tt][4 * rc + 1]);
                    pk[tt][rc][1] = pack2bf(sacc[tt][4 * rc + 2], sacc[tt][4 * rc + 3]);
                }

            // ---- in-register exchange (xor-32) -> pa[ks]: B-frag P^T[k][q=c5] ----
            bf16x8 pa[4];
#pragma unroll
            for (int tt = 0; tt < 2; ++tt) {
#pragma unroll
                for (int pr = 0; pr < 2; ++pr) {
                    unsigned int s0 = hi ? pk[tt][2 * pr][0] : pk[tt][2 * pr + 1][0];
                    unsigned int s1 = hi ? pk[tt][2 * pr][1] : pk[tt][2 * pr + 1][1];
                    unsigned int r0 = (unsigned int)__shfl_xor((int)s0, 32);
                    unsigned int r1 = (unsigned int)__shfl_xor((int)s1, 32);
                    u32x4 pw;
                    pw[0] = hi ? r0 : pk[tt][2 * pr][0];
                    pw[1] = hi ? r1 : pk[tt][2 * pr][1];
                    pw[2] = hi ? pk[tt][2 * pr + 1][0] : r0;
                    pw[3] = hi ? pk[tt][2 * pr + 1][1] : r1;
                    pa[2 * tt + pr] = __builtin_bit_cast(bf16x8, pw);
                }
            }

            // ---- PV (32x32x16): O^T[dout][q] += V^T[dout][kv] . P^T[kv][q] ----
            __builtin_amdgcn_s_setprio(1);
#pragma unroll
            for (int dt = 0; dt < 2; ++dt) {
#pragma unroll
                for (int ks = 0; ks < 4; ++ks) {
                    bf16x8 vf = *(const bf16x8*)((char*)(Vt + cur * 4096) +
                                (32 * dt + c5) * 128 + ((ks * 32 + hi * 16) ^ ((c5 & 7) << 4)));
                    oacc[h2][dt] = __builtin_amdgcn_mfma_f32_32x32x16_bf16(
                        vf, pa[ks], oacc[h2][dt], 0, 0, 0);
                }
            }
            __builtin_amdgcn_s_setprio(0);
        }

        if (t < 31) STAGE_WRITE(nxt);
        __syncthreads();
    }

    // ---- epilogue: two 128-row passes: O^T/l -> LDS transpose -> store ----
    float* OT = (float*)smem;   // [128 q][64 d], 256 B rows, XOR-swizzled
#pragma unroll
    for (int h2 = 0; h2 < 2; ++h2) {
        const float rinv = 1.0f / l_run[h2];
        {
            const int row = w * 32 + c5;
#pragma unroll
            for (int dt = 0; dt < 2; ++dt)
#pragma unroll
                for (int rc = 0; rc < 4; ++rc) {
                    f32x4 v;
#pragma unroll
                    for (int i = 0; i < 4; ++i) v[i] = oacc[h2][dt][4 * rc + i] * rinv;
                    *(f32x4*)((char*)OT + row * 256 +
                              (((32 * dt + 8 * rc + 4 * hi) * 4) ^ ((row & 7) << 4))) = v;
                }
        }
        __syncthreads();
        {
            const int row  = tid >> 1;          // 0..127
            const int half = tid & 1;           // d-half
            const int qrow = qb * 256 + h2 * 128 + row;
#pragma unroll
            for (int k = 0; k < 8; ++k) {
                f32x4 v = *(const f32x4*)((char*)OT + row * 256 +
                           ((128 * half + 16 * k) ^ ((row & 7) << 4)));
                *(f32x4*)(Op + (size_t)qrow * SROW + 32 * half + 4 * k) = v;
            }
        }
        if (h2 == 0) __syncthreads();
    }
}

extern "C" void kernel_launch(void* const* d_in, const int* in_sizes, int n_in,
                              void* d_out, int out_size, void* d_ws, size_t ws_size,
                              hipStream_t stream) {
    const float* V = (const float*)d_in[0];
    const float* K = (const float*)d_in[1];
    const float* Q = (const float*)d_in[2];
    const int*   M = (const int*)d_in[3];
    float*       O = (float*)d_out;
    // grid: 8 q-blocks x 16 heads x 4 batch = 512 blocks (exactly 2/CU), 256 threads
    attn_fwd<<<dim3(512), dim3(256), 0, stream>>>(V, K, Q, M, O);
}

// Round 10
// 128.669 us; speedup vs baseline: 3.5915x; 1.0285x over previous
//
#include <hip/hip_runtime.h>
#include <hip/hip_bf16.h>

typedef __attribute__((ext_vector_type(8))) short bf16x8;
typedef __attribute__((ext_vector_type(8))) unsigned short u16x8;
typedef __attribute__((ext_vector_type(16))) float f32x16;
typedef __attribute__((ext_vector_type(4))) float f32x4;
typedef __attribute__((ext_vector_type(4))) int i32x4;
typedef __attribute__((ext_vector_type(4))) unsigned int u32x4;
typedef __attribute__((ext_vector_type(2))) unsigned int u32x2;

__device__ __forceinline__ unsigned short f2bf(float f) {
    union { __hip_bfloat16 h; unsigned short u; } cv;
    cv.h = __float2bfloat16(f);
    return cv.u;
}
__device__ __forceinline__ unsigned int pack2bf(float a, float b) {
    return (unsigned int)f2bf(a) | ((unsigned int)f2bf(b) << 16);
}
// permlane32_swap: D' = {a.lo, b.lo}, S' = {a.hi, b.hi} — VALU cross-lane
// exchange, replaces ds_bpermute (~100cyc LDS latency) on the softmax->PV
// critical path (T12 primitive, m255: 1.20x vs bpermute).
__device__ __forceinline__ u32x2 perm32(unsigned int a, unsigned int b) {
#if __has_builtin(__builtin_amdgcn_permlane32_swap)
    return __builtin_amdgcn_permlane32_swap(a, b, false, false);
#else
    asm("v_permlane32_swap_b32 %0, %1" : "+v"(a), "+v"(b));
    u32x2 r; r[0] = a; r[1] = b; return r;
#endif
}
// xor-32 pair for a float: returns (own-half value, partner-half value)
__device__ __forceinline__ void swap32f(float v, float& x, float& y) {
    u32x2 r = perm32(__builtin_bit_cast(unsigned int, v),
                     __builtin_bit_cast(unsigned int, v));
    x = __builtin_bit_cast(float, r[0]);
    y = __builtin_bit_cast(float, r[1]);
}
#define MAX4(v, i) fmaxf(fmaxf(v[i], v[(i)+1]), fmaxf(v[(i)+2], v[(i)+3]))
#define SUM4(v, i) ((v[i] + v[(i)+1]) + (v[(i)+2] + v[(i)+3]))

// (256,2): 256-VGPR cap — the 128-cap variant spilled accumulators (round 6:
// 1.6 GB scratch traffic). High-VGPR deep waves beat occupancy here (m214).
// QBLK=256: two q-halves per block -> staging cost amortized 2x (round 9).
__global__ __launch_bounds__(256, 2) void attn_fwd(
    const float* __restrict__ Vg, const float* __restrict__ Kg,
    const float* __restrict__ Qg, const int* __restrict__ Mg,
    float* __restrict__ Og)
{
    constexpr int S = 2048, H = 16, D = 64, SROW = H * D;
    constexpr float CST = 0.03125f * 1.44269504088896f;  // (1/sqrt(1024))·log2(e)

    // 32 KB: K dbuf 16K | VT dbuf 16K. Epilogue reuses it as O^T (2 passes).
    __shared__ char smem[32768];
    __shared__ int Tf[32];                                   // per-KV-tile mask flags
    unsigned short* Kl  = (unsigned short*)smem;             // [2][64*64] bf16 [kv][d]
    unsigned short* Vt  = (unsigned short*)(smem + 16384);   // [2][64*64] bf16 [d][kv]

    const int tid  = threadIdx.x;
    const int lane = tid & 63;
    const int w    = tid >> 6;
    const int c5   = lane & 31;   // fragment row/col index (= this lane's q-row)
    const int hi   = lane >> 5;   // half-wave index

    // T1: bijective XCD swizzle (512 blocks, 8 XCDs, 64 per XCD)
    const int logical = (blockIdx.x & 7) * 64 + (blockIdx.x >> 3);
    const int qb  = logical & 7;          // 8 q-blocks of 256 rows
    const int h   = (logical >> 3) & 15;
    const int b   = logical >> 7;

    const int q0 = qb * 256 + w * 32;     // + 128*h2 + c5 per half

    const size_t base = ((size_t)b * S * H + h) * D;
    const float* Qp = Qg + base;
    const float* Kp = Kg + base;
    const float* Vp = Vg + base;
    float*       Op = Og + base;
    const int*   Mp = Mg + b * S;

    // ---- per-tile mask flags (once per block) ----
    if (tid < 32) Tf[tid] = 0;
    __syncthreads();
    {
        const int* mp = Mp + tid * 8;
        i32x4 m0 = *(const i32x4*)mp;
        i32x4 m1 = *(const i32x4*)(mp + 4);
        int anyz = 0;
#pragma unroll
        for (int j = 0; j < 4; ++j) anyz |= (m0[j] == 0) | (m1[j] == 0);
        if (anyz) atomicOr(&Tf[tid >> 3], 1);
    }

    // staging coords
    const int kr  = tid >> 2;          // K-stage row 0..63
    const int kc0 = (tid & 3) << 4;    // K-stage col {0,16,32,48}
    const int vk  = (tid & 31) << 1;   // V-stage kv row pair base
    const int vd0 = (tid >> 5) << 3;   // V-stage d base {0..56}

    // ---- Q fragments, both halves, pre-scaled by CST ----
    bf16x8 qf[2][4];
#pragma unroll
    for (int h2 = 0; h2 < 2; ++h2)
#pragma unroll
        for (int kc = 0; kc < 4; ++kc) {
            const float* qr = Qp + (size_t)(q0 + 128 * h2 + c5) * SROW + kc * 16 + hi * 8;
            f32x4 x = *(const f32x4*)qr;
            f32x4 y = *(const f32x4*)(qr + 4);
            bf16x8 f;
#pragma unroll
            for (int j = 0; j < 4; ++j) {
                f[j]     = (short)f2bf(x[j] * CST);
                f[4 + j] = (short)f2bf(y[j] * CST);
            }
            qf[h2][kc] = f;
        }

    f32x16 oacc[2][2];
#pragma unroll
    for (int h2 = 0; h2 < 2; ++h2)
#pragma unroll
        for (int dt = 0; dt < 2; ++dt)
#pragma unroll
            for (int r = 0; r < 16; ++r) oacc[h2][dt][r] = 0.0f;
    float m_run[2] = {-INFINITY, -INFINITY};
    float l_run[2] = {0.0f, 0.0f};

    f32x4 kstg[4], vstg[4];

    auto STAGE_LOAD = [&](int t) {
        const int k0 = t * 64;
        const float* src = Kp + (size_t)(k0 + kr) * SROW + kc0;
        kstg[0] = *(const f32x4*)(src);
        kstg[1] = *(const f32x4*)(src + 4);
        kstg[2] = *(const f32x4*)(src + 8);
        kstg[3] = *(const f32x4*)(src + 12);
        const float* s0 = Vp + (size_t)(k0 + vk) * SROW + vd0;
        const float* s1 = s0 + SROW;
        vstg[0] = *(const f32x4*)(s0);
        vstg[1] = *(const f32x4*)(s0 + 4);
        vstg[2] = *(const f32x4*)(s1);
        vstg[3] = *(const f32x4*)(s1 + 4);
    };

    auto STAGE_WRITE = [&](int buf) {
        u16x8 w0, w1;
#pragma unroll
        for (int j = 0; j < 4; ++j) {
            w0[j]     = f2bf(kstg[0][j]);
            w0[4 + j] = f2bf(kstg[1][j]);
            w1[j]     = f2bf(kstg[2][j]);
            w1[4 + j] = f2bf(kstg[3][j]);
        }
        char* kb = (char*)(Kl + buf * 4096) + kr * 128;
        *(u16x8*)(kb + ((kc0 * 2)      ^ ((kr & 7) << 4))) = w0;
        *(u16x8*)(kb + ((kc0 * 2 + 16) ^ ((kr & 7) << 4))) = w1;
        char* vbase = (char*)(Vt + buf * 4096);
#pragma unroll
        for (int j = 0; j < 8; ++j) {
            int d = vd0 + j;
            float lo = (j < 4) ? vstg[0][j] : vstg[1][j - 4];
            float hv = (j < 4) ? vstg[2][j] : vstg[3][j - 4];
            unsigned int val = (unsigned int)f2bf(lo) | ((unsigned int)f2bf(hv) << 16);
            *(unsigned int*)(vbase + d * 128 + ((vk * 2) ^ ((d & 7) << 4))) = val;
        }
    };

    // ---- prologue ----
    STAGE_LOAD(0);
    STAGE_WRITE(0);
    __syncthreads();   // also publishes Tf

    for (int t = 0; t < 32; ++t) {
        const int cur = t & 1;
        const int nxt = cur ^ 1;
        const int k0  = t * 64;

        if (t < 31) STAGE_LOAD(t + 1);   // T14: issue early, write after compute

#pragma unroll
        for (int h2 = 0; h2 < 2; ++h2) {
            // ---- swapped QK^T (32x32x16): S^T[kv=32tt+(r&3)+8(r>>2)+4hi][q=c5] ----
            f32x16 sacc[2];
#pragma unroll
            for (int tt = 0; tt < 2; ++tt)
#pragma unroll
                for (int r = 0; r < 16; ++r) sacc[tt][r] = 0.0f;

            __builtin_amdgcn_s_setprio(1);
#pragma unroll
            for (int tt = 0; tt < 2; ++tt) {
#pragma unroll
                for (int kc = 0; kc < 4; ++kc) {
                    bf16x8 kf = *(const bf16x8*)((char*)(Kl + cur * 4096) +
                                (32 * tt + c5) * 128 + ((kc * 32 + hi * 16) ^ ((c5 & 7) << 4)));
                    sacc[tt] = __builtin_amdgcn_mfma_f32_32x32x16_bf16(
                        kf, qf[h2][kc], sacc[tt], 0, 0, 0);
                }
            }
            __builtin_amdgcn_s_setprio(0);

            // ---- mask (rare slow path; block-uniform branch) ----
            if (Tf[t]) {
                const int* mp = Mp + k0;
#pragma unroll
                for (int tt = 0; tt < 2; ++tt)
#pragma unroll
                    for (int rc = 0; rc < 4; ++rc) {
                        i32x4 mv = *(const i32x4*)(mp + 32 * tt + 8 * rc + 4 * hi);
#pragma unroll
                        for (int r = 0; r < 4; ++r)
                            if (!mv[r]) sacc[tt][4 * rc + r] = -1e20f;
                    }
            }

            // ---- online softmax: tree max + permlane xor-32 ----
            float mA = fmaxf(MAX4(sacc[0], 0), MAX4(sacc[0], 4));
            float mB = fmaxf(MAX4(sacc[0], 8), MAX4(sacc[0], 12));
            float mC = fmaxf(MAX4(sacc[1], 0), MAX4(sacc[1], 4));
            float mD = fmaxf(MAX4(sacc[1], 8), MAX4(sacc[1], 12));
            float mx = fmaxf(fmaxf(mA, mB), fmaxf(mC, mD));
            {
                float x, y;
                swap32f(mx, x, y);
                mx = fmaxf(x, y);
            }

            // T13 defer-max: skip rescale while max growth <= 8
            if (!__all(mx <= m_run[h2] + 8.0f)) {
                float mn = fmaxf(m_run[h2], mx);
                float alpha = __builtin_amdgcn_exp2f(m_run[h2] - mn);
                m_run[h2] = mn;
                l_run[h2] *= alpha;
#pragma unroll
                for (int dt = 0; dt < 2; ++dt)
#pragma unroll
                    for (int r = 0; r < 16; ++r) oacc[h2][dt][r] *= alpha;
            }

            // p = exp2(lg - m)
#pragma unroll
            for (int tt = 0; tt < 2; ++tt)
#pragma unroll
                for (int r = 0; r < 16; ++r)
                    sacc[tt][r] = __builtin_amdgcn_exp2f(sacc[tt][r] - m_run[h2]);

            // row sum: pairwise tree + permlane xor-32
            float sm = (SUM4(sacc[0], 0) + SUM4(sacc[0], 4)) +
                       (SUM4(sacc[0], 8) + SUM4(sacc[0], 12)) +
                       ((SUM4(sacc[1], 0) + SUM4(sacc[1], 4)) +
                        (SUM4(sacc[1], 8) + SUM4(sacc[1], 12)));
            {
                float x, y;
                swap32f(sm, x, y);
                sm = x + y;
            }
            l_run[h2] += sm;

            // ---- P -> bf16 pack ----
            unsigned int pk[2][4][2];
#pragma unroll
            for (int tt = 0; tt < 2; ++tt)
#pragma unroll
                for (int rc = 0; rc < 4; ++rc) {
                    pk[tt][rc][0] = pack2bf(sacc[tt][4 * rc],     sacc[tt][4 * rc + 1]);
                    pk[tt][rc][1] = pack2bf(sacc[tt][4 * rc + 2], sacc[tt][4 * rc + 3]);
                }

            // ---- permlane32_swap exchange -> pa[ks]: B-frag P^T[k][q=c5] ----
            // (D',S') = swap(x,y): D' = {x.lo, y.lo} = pw[word], S' = {x.hi, y.hi}
            bf16x8 pa[4];
#pragma unroll
            for (int tt = 0; tt < 2; ++tt) {
#pragma unroll
                for (int pr = 0; pr < 2; ++pr) {
                    u32x2 sw0 = perm32(pk[tt][2 * pr][0], pk[tt][2 * pr + 1][0]);
                    u32x2 sw1 = perm32(pk[tt][2 * pr][1], pk[tt][2 * pr + 1][1]);
                    u32x4 pw;
                    pw[0] = sw0[0];
                    pw[1] = sw1[0];
                    pw[2] = sw0[1];
                    pw[3] = sw1[1];
                    pa[2 * tt + pr] = __builtin_bit_cast(bf16x8, pw);
                }
            }

            // ---- PV (32x32x16): O^T[dout][q] += V^T[dout][kv] . P^T[kv][q] ----
            __builtin_amdgcn_s_setprio(1);
#pragma unroll
            for (int dt = 0; dt < 2; ++dt) {
#pragma unroll
                for (int ks = 0; ks < 4; ++ks) {
                    bf16x8 vf = *(const bf16x8*)((char*)(Vt + cur * 4096) +
                                (32 * dt + c5) * 128 + ((ks * 32 + hi * 16) ^ ((c5 & 7) << 4)));
                    oacc[h2][dt] = __builtin_amdgcn_mfma_f32_32x32x16_bf16(
                        vf, pa[ks], oacc[h2][dt], 0, 0, 0);
                }
            }
            __builtin_amdgcn_s_setprio(0);
        }

        if (t < 31) STAGE_WRITE(nxt);
        __syncthreads();
    }

    // ---- epilogue: two 128-row passes: O^T/l -> LDS transpose -> store ----
    float* OT = (float*)smem;   // [128 q][64 d], 256 B rows, XOR-swizzled
#pragma unroll
    for (int h2 = 0; h2 < 2; ++h2) {
        const float rinv = 1.0f / l_run[h2];
        {
            const int row = w * 32 + c5;
#pragma unroll
            for (int dt = 0; dt < 2; ++dt)
#pragma unroll
                for (int rc = 0; rc < 4; ++rc) {
                    f32x4 v;
#pragma unroll
                    for (int i = 0; i < 4; ++i) v[i] = oacc[h2][dt][4 * rc + i] * rinv;
                    *(f32x4*)((char*)OT + row * 256 +
                              (((32 * dt + 8 * rc + 4 * hi) * 4) ^ ((row & 7) << 4))) = v;
                }
        }
        __syncthreads();
        {
            const int row  = tid >> 1;          // 0..127
            const int half = tid & 1;           // d-half
            const int qrow = qb * 256 + h2 * 128 + row;
#pragma unroll
            for (int k = 0; k < 8; ++k) {
                f32x4 v = *(const f32x4*)((char*)OT + row * 256 +
                           ((128 * half + 16 * k) ^ ((row & 7) << 4)));
                *(f32x4*)(Op + (size_t)qrow * SROW + 32 * half + 4 * k) = v;
            }
        }
        if (h2 == 0) __syncthreads();
    }
}

extern "C" void kernel_launch(void* const* d_in, const int* in_sizes, int n_in,
                              void* d_out, int out_size, void* d_ws, size_t ws_size,
                              hipStream_t stream) {
    const float* V = (const float*)d_in[0];
    const float* K = (const float*)d_in[1];
    const float* Q = (const float*)d_in[2];
    const int*   M = (const int*)d_in[3];
    float*       O = (float*)d_out;
    // grid: 8 q-blocks x 16 heads x 4 batch = 512 blocks (exactly 2/CU), 256 threads
    attn_fwd<<<dim3(512), dim3(256), 0, stream>>>(V, K, Q, M, O);
}